// Round 6
// baseline (289.828 us; speedup 1.0000x reference)
//
#include <hip/hip_runtime.h>
#include <math.h>

#define N_NODES 8192
#define N_EDGES 65536
#define F_IN    512
#define HID1    4096
#define HID2    1024
#define F_OUT   10
#define H3_STRIDE 16
#define W3B_STRIDE 1032   // padded K-stride of bf16 W3^T rows

typedef __bf16 bf16x8 __attribute__((ext_vector_type(8)));
typedef float floatx4 __attribute__((ext_vector_type(4)));
typedef float floatx16 __attribute__((ext_vector_type(16)));

static __device__ __forceinline__ unsigned short f2bf(float f) {
    union { float f; unsigned u; } v; v.f = f;
    unsigned r = v.u + 0x7fffu + ((v.u >> 16) & 1u);   // RNE
    return (unsigned short)(r >> 16);
}
static __device__ __forceinline__ float bf2f(unsigned short u) {
    union { unsigned u; float f; } v; v.u = ((unsigned)u) << 16;
    return v.f;
}
static __device__ __forceinline__ void unpack8(uint4 r, float* f) {
    union { unsigned u; float v; } c;
    c.u = r.x << 16;          f[0] = c.v;
    c.u = r.x & 0xffff0000u;  f[1] = c.v;
    c.u = r.y << 16;          f[2] = c.v;
    c.u = r.y & 0xffff0000u;  f[3] = c.v;
    c.u = r.z << 16;          f[4] = c.v;
    c.u = r.z & 0xffff0000u;  f[5] = c.v;
    c.u = r.w << 16;          f[6] = c.v;
    c.u = r.w & 0xffff0000u;  f[7] = c.v;
}
static __device__ __forceinline__ uint4 pack8(const float* f) {
    uint4 o;
    o.x = (unsigned)f2bf(f[0]) | ((unsigned)f2bf(f[1]) << 16);
    o.y = (unsigned)f2bf(f[2]) | ((unsigned)f2bf(f[3]) << 16);
    o.z = (unsigned)f2bf(f[4]) | ((unsigned)f2bf(f[5]) << 16);
    o.w = (unsigned)f2bf(f[6]) | ((unsigned)f2bf(f[7]) << 16);
    return o;
}

// ---------------------------------------------------------------------------
// hist: grid-wide atomic histogram of dst into deg[] (deg pre-zeroed via
// hipMemsetAsync). Replaces the single-block LDS-histogram monolith.
// ---------------------------------------------------------------------------
__global__ __launch_bounds__(256) void hist_kernel(
        const int* __restrict__ ei, int* __restrict__ deg) {
    int e = blockIdx.x * 256 + threadIdx.x;
    atomicAdd(&deg[ei[N_EDGES + e]], 1);
}

// ---------------------------------------------------------------------------
// scan (one block): exclusive scan of deg -> row_ptr; zero cnt.
// ---------------------------------------------------------------------------
__global__ __launch_bounds__(1024) void scan_kernel(
        const int* __restrict__ deg, int* __restrict__ row_ptr,
        int* __restrict__ cnt) {
    __shared__ int sums[1024];
    int t = threadIdx.x;
    int base = t * 8;
    int4 d0 = ((const int4*)deg)[t * 2];
    int4 d1 = ((const int4*)deg)[t * 2 + 1];
    int dv[8] = {d0.x, d0.y, d0.z, d0.w, d1.x, d1.y, d1.z, d1.w};
    int local[8], run = 0;
#pragma unroll
    for (int i = 0; i < 8; i++) { local[i] = run; run += dv[i]; }
    sums[t] = run;
    ((int4*)cnt)[t * 2] = make_int4(0, 0, 0, 0);
    ((int4*)cnt)[t * 2 + 1] = make_int4(0, 0, 0, 0);
    __syncthreads();
    for (int off = 1; off < 1024; off <<= 1) {
        int val = (t >= off) ? sums[t - off] : 0;
        __syncthreads();
        sums[t] += val;
        __syncthreads();
    }
    int offset = (t == 0) ? 0 : sums[t - 1];
#pragma unroll
    for (int i = 0; i < 8; i++) row_ptr[base + i] = offset + local[i];
    if (t == 1023) row_ptr[N_NODES] = sums[1023];
}

// ---------------------------------------------------------------------------
// megaprep: fill CSR (blocks 0..255) + xcvt (256..4351) + W1^T (4352..6399)
// + W2^T (6400..10495) + W3 bf16 cvt (10496). One launch.
// ---------------------------------------------------------------------------
static __device__ __forceinline__ void transpose_body(
        const float* __restrict__ W, unsigned short* __restrict__ Wt,
        int K, int N, int k0, int n0, int tid, float (*t)[33]) {
    int c = tid & 31, r8 = tid >> 5;
#pragma unroll
    for (int i = 0; i < 4; i++) {
        int r = r8 + i * 8;
        t[r][c] = W[(size_t)(k0 + r) * N + n0 + c];
    }
    __syncthreads();
#pragma unroll
    for (int i = 0; i < 4; i++) {
        int r = r8 + i * 8;
        Wt[(size_t)(n0 + r) * K + k0 + c] = f2bf(t[c][r]);
    }
}

__global__ __launch_bounds__(256) void megaprep_kernel(
        const int* __restrict__ ei, const int* __restrict__ deg,
        const int* __restrict__ row_ptr, int* __restrict__ cnt,
        int* __restrict__ csr_src, float* __restrict__ csr_w,
        const float* __restrict__ x, unsigned short* __restrict__ xb,
        const float* __restrict__ W1, unsigned short* __restrict__ W1t,
        const float* __restrict__ W2, unsigned short* __restrict__ W2t,
        const float* __restrict__ W3, unsigned short* __restrict__ w3b) {
    __shared__ float t[32][33];
    int b = blockIdx.x, tid = threadIdx.x;
    if (b < 256) {
        int e = b * 256 + tid;
        int s = ei[e];
        int d = ei[N_EDGES + e];
        int slot = row_ptr[d] + atomicAdd(&cnt[d], 1);
        csr_src[slot] = s;
        csr_w[slot] = rsqrtf((float)((deg[s] + 1) * (deg[d] + 1)));
    } else if (b < 4352) {
        int i = (b - 256) * 256 + tid;
        float4 a = ((const float4*)x)[i];
        ushort4 o;
        o.x = f2bf(a.x); o.y = f2bf(a.y); o.z = f2bf(a.z); o.w = f2bf(a.w);
        ((ushort4*)xb)[i] = o;
    } else if (b < 6400) {
        int bb = b - 4352;                       // W1: K=512, N=4096
        transpose_body(W1, W1t, F_IN, HID1, (bb >> 7) * 32, (bb & 127) * 32, tid, t);
    } else if (b < 10496) {
        int bb = b - 6400;                       // W2: K=4096, N=1024
        transpose_body(W2, W2t, HID1, HID2, (bb >> 5) * 32, (bb & 31) * 32, tid, t);
    } else {
        // W3 [1024,10] f32 -> w3b [10][W3B_STRIDE] bf16 (transposed)
        for (int i = tid; i < HID2 * F_OUT; i += 256) {
            int k = i / F_OUT, c = i % F_OUT;
            w3b[c * W3B_STRIDE + k] = f2bf(W3[i]);
        }
    }
}

// ---------------------------------------------------------------------------
// agg1: agg_x[v,:] = sum_e w_e*xb[src,:] + xb[v,:]/(deg+1) -> bf16
// ---------------------------------------------------------------------------
__global__ __launch_bounds__(256) void agg1_kernel(
        const unsigned short* __restrict__ xb, const int* __restrict__ row_ptr,
        const int* __restrict__ csr_src, const float* __restrict__ csr_w,
        const int* __restrict__ deg, unsigned short* __restrict__ out) {
    int v = blockIdx.x * 4 + (threadIdx.x >> 6);
    int t = threadIdx.x & 63;
    const uint4* xp = (const uint4*)xb;        // row stride 64 uint4
    float sw = 1.0f / (float)(deg[v] + 1);
    float acc[8], tmp[8];
    unpack8(xp[(size_t)v * 64 + t], tmp);
#pragma unroll
    for (int j = 0; j < 8; j++) acc[j] = sw * tmp[j];
    int e = row_ptr[v], end = row_ptr[v + 1];
    for (; e + 4 <= end; e += 4) {
        int s0 = csr_src[e], s1 = csr_src[e + 1];
        int s2 = csr_src[e + 2], s3 = csr_src[e + 3];
        float w0 = csr_w[e], w1 = csr_w[e + 1];
        float w2 = csr_w[e + 2], w3 = csr_w[e + 3];
        float f0[8], f1[8], f2[8], f3[8];
        unpack8(xp[(size_t)s0 * 64 + t], f0);
        unpack8(xp[(size_t)s1 * 64 + t], f1);
        unpack8(xp[(size_t)s2 * 64 + t], f2);
        unpack8(xp[(size_t)s3 * 64 + t], f3);
#pragma unroll
        for (int j = 0; j < 8; j++)
            acc[j] += w0 * f0[j] + w1 * f1[j] + w2 * f2[j] + w3 * f3[j];
    }
    for (; e < end; e++) {
        int s = csr_src[e];
        float w = csr_w[e];
        float f0[8];
        unpack8(xp[(size_t)s * 64 + t], f0);
#pragma unroll
        for (int j = 0; j < 8; j++) acc[j] += w * f0[j];
    }
    ((uint4*)out)[(size_t)v * 64 + t] = pack8(acc);
}

// ---------------------------------------------------------------------------
// agg2 + gemm3 fused.
// ---------------------------------------------------------------------------
__global__ __launch_bounds__(256) void agg2_gemm3_kernel(
        const unsigned short* __restrict__ h, const int* __restrict__ row_ptr,
        const int* __restrict__ csr_src, const float* __restrict__ csr_w,
        const int* __restrict__ deg, const float* __restrict__ b2,
        const unsigned short* __restrict__ w3b, float* __restrict__ H3) {
    __shared__ unsigned short w3s[F_OUT * W3B_STRIDE];   // ~20.2 KB
    __shared__ float red[4][F_OUT];
    int tid = threadIdx.x;
    for (int i = tid; i < F_OUT * W3B_STRIDE; i += 256) w3s[i] = w3b[i];
    __syncthreads();
    int half = tid >> 7;
    int t = tid & 127;
    int v = blockIdx.x * 2 + half;
    const uint4* hp = (const uint4*)h;   // row stride 128 uint4
    float sw = 1.0f / (float)(deg[v] + 1);
    float acc[8], tmp[8];
    unpack8(hp[(size_t)v * 128 + t], tmp);
#pragma unroll
    for (int j = 0; j < 8; j++) acc[j] = sw * tmp[j];
    int e = row_ptr[v], end = row_ptr[v + 1];
    for (; e + 4 <= end; e += 4) {
        int s0 = csr_src[e], s1 = csr_src[e + 1];
        int s2 = csr_src[e + 2], s3 = csr_src[e + 3];
        float w0 = csr_w[e], w1 = csr_w[e + 1];
        float w2 = csr_w[e + 2], w3 = csr_w[e + 3];
        float f0[8], f1[8], f2[8], f3[8];
        unpack8(hp[(size_t)s0 * 128 + t], f0);
        unpack8(hp[(size_t)s1 * 128 + t], f1);
        unpack8(hp[(size_t)s2 * 128 + t], f2);
        unpack8(hp[(size_t)s3 * 128 + t], f3);
#pragma unroll
        for (int j = 0; j < 8; j++)
            acc[j] += w0 * f0[j] + w1 * f1[j] + w2 * f2[j] + w3 * f3[j];
    }
    for (; e < end; e++) {
        int s = csr_src[e];
        float w = csr_w[e];
        float f0[8];
        unpack8(hp[(size_t)s * 128 + t], f0);
#pragma unroll
        for (int j = 0; j < 8; j++) acc[j] += w * f0[j];
    }
    float4 b4a = ((const float4*)b2)[t * 2];
    float4 b4b = ((const float4*)b2)[t * 2 + 1];
    acc[0] = fmaxf(acc[0] + b4a.x, 0.0f); acc[1] = fmaxf(acc[1] + b4a.y, 0.0f);
    acc[2] = fmaxf(acc[2] + b4a.z, 0.0f); acc[3] = fmaxf(acc[3] + b4a.w, 0.0f);
    acc[4] = fmaxf(acc[4] + b4b.x, 0.0f); acc[5] = fmaxf(acc[5] + b4b.y, 0.0f);
    acc[6] = fmaxf(acc[6] + b4b.z, 0.0f); acc[7] = fmaxf(acc[7] + b4b.w, 0.0f);

    float partial[F_OUT];
#pragma unroll
    for (int c = 0; c < F_OUT; c++) {
        float wf[8];
        unpack8(*(const uint4*)&w3s[c * W3B_STRIDE + t * 8], wf);
        partial[c] = acc[0] * wf[0] + acc[1] * wf[1] + acc[2] * wf[2] + acc[3] * wf[3]
                   + acc[4] * wf[4] + acc[5] * wf[5] + acc[6] * wf[6] + acc[7] * wf[7];
    }
#pragma unroll
    for (int c = 0; c < F_OUT; c++) {
#pragma unroll
        for (int off = 32; off > 0; off >>= 1)
            partial[c] += __shfl_xor(partial[c], off, 64);
    }
    int wave = tid >> 6, lane = tid & 63;
    if (lane == 0) {
#pragma unroll
        for (int c = 0; c < F_OUT; c++) red[wave][c] = partial[c];
    }
    __syncthreads();
    if (tid < 2 * F_OUT) {
        int hh = tid / F_OUT, c = tid % F_OUT;
        H3[(size_t)(blockIdx.x * 2 + hh) * H3_STRIDE + c] =
            red[hh * 2][c] + red[hh * 2 + 1][c];
    }
}

// ---------------------------------------------------------------------------
// Shared LDS swizzle pieces (refcheck-verified in R4/R5): 256-row x 32-col
// bf16 buffer (16 KB), 256B super-rows of 16 chunks, chunk XOR by
// (row>>2)&3. Uniform banks for wave64 b128 reads (measured 0 conflicts).
// ---------------------------------------------------------------------------
#define P8_OFF(R_, lc_) ((((R_) >> 2) * 128) + (((((R_) & 3) << 2) | (lc_)) ^ (((R_) >> 2) & 3)) * 8)

// Stage one 16KB buffer (1024 16B slots) with linear LDS dest +
// inverse-swizzled global source. Lbuf_ = ushort* to buffer base.
#define Q4_STAGE(Lbuf_, base_, k0_) do {                                       \
    unsigned short* L_ = (Lbuf_);                                              \
    _Pragma("unroll")                                                          \
    for (int j = 0; j < 2; j++) {                                              \
        int sl = j * 512 + tid;                                                \
        int s4 = sl >> 4, cs = sl & 15;                                        \
        int csp = cs ^ (s4 & 3);                                               \
        int grow = s4 * 4 + (csp >> 2);                                        \
        int gcol = (csp & 3) * 8;                                              \
        __builtin_amdgcn_global_load_lds(                                      \
            (const __attribute__((address_space(1))) void*)((base_) + (size_t)grow * K + (k0_) + gcol), \
            (__attribute__((address_space(3))) void*)(&L_[sl * 8]), 16, 0, 0); \
    }                                                                          \
} while (0)

// P8 staging (gemm1): buffer index (dbuf,mat,khalf), khalf adds k-offset 32.
#define P8_STAGE(mat_, kh_, dd_, base_, k0_) \
    Q4_STAGE(lds + ((dd_) * 4 + (mat_) * 2 + (kh_)) * 8192, base_, (k0_) + (kh_) * 32)

#define P8_MAIN_LOOP(NT_)                                                      \
    P8_STAGE(0, 0, 0, Abase, 0);                                               \
    P8_STAGE(1, 0, 0, Bbase, 0);                                               \
    P8_STAGE(0, 1, 0, Abase, 0);                                               \
    P8_STAGE(1, 1, 0, Bbase, 0);                                               \
    asm volatile("s_waitcnt vmcnt(4)" ::: "memory");                           \
    __builtin_amdgcn_s_barrier();                                              \
    for (int t = 0; t < (NT_); t++) {                                          \
        int d = t & 1, dn = d ^ 1;                                             \
        int k1 = (t + 1) * 64;                                                 \
        _Pragma("unroll")                                                      \
        for (int kk = 0; kk < 4; kk++) {                                       \
            if (kk == 2) {                                                     \
                if (t + 1 < (NT_))                                             \
                    asm volatile("s_waitcnt vmcnt(4)" ::: "memory");           \
                else                                                           \
                    asm volatile("s_waitcnt vmcnt(0)" ::: "memory");           \
                __builtin_amdgcn_s_barrier();                                  \
            }                                                                  \
            int kh = kk >> 1;                                                  \
            int lc0 = (kk & 1) * 2 + lhalf;                                    \
            const unsigned short* Ak = lds + (d * 4 + kh) * 8192;              \
            const unsigned short* Bk = lds + (d * 4 + 2 + kh) * 8192;          \
            bf16x8 af[4], bfr[2];                                              \
            _Pragma("unroll")                                                  \
            for (int mt = 0; mt < 4; mt++) {                                   \
                int R = wm * 128 + mt * 32 + lrow;                             \
                af[mt] = *(const bf16x8*)&Ak[P8_OFF(R, lc0)];                  \
            }                                                                  \
            _Pragma("unroll")                                                  \
            for (int nt = 0; nt < 2; nt++) {                                   \
                int R = wn * 64 + nt * 32 + lrow;                              \
                bfr[nt] = *(const bf16x8*)&Bk[P8_OFF(R, lc0)];                 \
            }                                                                  \
            if (t + 1 < (NT_)) {                                               \
                if (kk == 0)      P8_STAGE(0, 0, dn, Abase, k1);               \
                else if (kk == 1) P8_STAGE(1, 0, dn, Bbase, k1);               \
                else if (kk == 2) P8_STAGE(0, 1, dn, Abase, k1);               \
                else              P8_STAGE(1, 1, dn, Bbase, k1);               \
            }                                                                  \
            __builtin_amdgcn_s_barrier();                                      \
            __builtin_amdgcn_s_setprio(1);                                     \
            _Pragma("unroll")                                                  \
            for (int mt = 0; mt < 4; mt++)                                     \
                _Pragma("unroll")                                              \
                for (int nt = 0; nt < 2; nt++)                                 \
                    acc[mt][nt] = __builtin_amdgcn_mfma_f32_32x32x16_bf16(     \
                        af[mt], bfr[nt], acc[mt][nt], 0, 0, 0);                \
            __builtin_amdgcn_s_setprio(0);                                     \
            if (kk == 0 || kk == 2) __builtin_amdgcn_s_barrier();              \
        }                                                                      \
        asm volatile("s_waitcnt vmcnt(4)" ::: "memory");                       \
        __builtin_amdgcn_s_barrier();                                          \
    }

// ---------------------------------------------------------------------------
// GEMM1: agg_x[8192,512] @ W1t -> relu(+b1) -> h1 bf16 [8192,4096].
// 512 blocks (16 ntiles x 32 mtiles), 512 threads, 8-phase schedule (R4).
// ---------------------------------------------------------------------------
__global__ __launch_bounds__(512, 2) void gemm1_pipe8_kernel(
        const unsigned short* __restrict__ A,   // [8192,512] bf16
        const unsigned short* __restrict__ Bt,  // [4096,512] bf16
        const float* __restrict__ bias,         // [4096]
        unsigned short* __restrict__ C) {       // [8192,4096] bf16
    __shared__ unsigned short lds[65536];       // 128 KB
    const int K = F_IN, N = HID1;
    int tid = threadIdx.x;
    int wave = tid >> 6, lane = tid & 63;
    int wm = wave >> 2, wn = wave & 3;          // 2M x 4N, wave-tile 128x64
    int lrow = lane & 31, lhalf = lane >> 5;

    int b = blockIdx.x;
    int GN = HID1 >> 8;                         // 16
    int ntile = (b >> 3) % GN;
    int mtile = ((b >> 3) / GN) * 8 + (b & 7);  // 0..31
    int m0 = mtile * 256, n0 = ntile * 256;

    const unsigned short* Abase = A + (size_t)m0 * K;
    const unsigned short* Bbase = Bt + (size_t)n0 * K;

    floatx16 acc[4][2] = {};
    P8_MAIN_LOOP(8)                             // K=512 -> 8 K-tiles

#pragma unroll
    for (int mt = 0; mt < 4; mt++) {
#pragma unroll
        for (int nt = 0; nt < 2; nt++) {
            int col = n0 + wn * 64 + nt * 32 + lrow;
            float bv = bias[col];
#pragma unroll
            for (int reg = 0; reg < 16; reg++) {
                int row = m0 + wm * 128 + mt * 32 + (reg & 3) + 8 * (reg >> 2) + 4 * lhalf;
                float v = fmaxf(acc[mt][nt][reg] + bv, 0.0f);
                C[(size_t)row * N + col] = f2bf(v);
            }
        }
    }
}

// ---------------------------------------------------------------------------
// GEMM2 split-K quad-buffer (R6): BK=32, 4 buffer slots (128 KB), prefetch
// 3 tiles ahead, ONE barrier + one counted vmcnt per tile (no intra-tile
// barriers -> the 2 waves/SIMD drift and overlap ds_read with MFMA).
// Per tile: 2 k16-phases {6 ds_reads, stage A or B of t+3, setprio, 8 MFMA}.
// vmcnt chain: t+3<NT -> 8 (t+2,t+3 in flight); t+2<NT -> 4; else 0.
// Hazards: stage at t overwrites slot of t-1 (reads retired before the
// t-1 -> t barrier); per-wave vmcnt + barrier = collective buffer readiness.
// ---------------------------------------------------------------------------
__global__ __launch_bounds__(512, 2) void gemm2_q4_split_kernel(
        const unsigned short* __restrict__ A,   // [8192,4096] bf16 (h1)
        const unsigned short* __restrict__ Bt,  // [1024,4096] bf16 (W2t)
        unsigned short* __restrict__ Ca,        // [8192,1024] bf16 partial k0
        unsigned short* __restrict__ Cb) {      // [8192,1024] bf16 partial k1
    __shared__ unsigned short lds[65536];       // 128 KB = 4 slots x (A+B 16KB)
    const int K = HID1;                         // row stride of A and Bt
    const int N = HID2;
    int tid = threadIdx.x;
    int wave = tid >> 6, lane = tid & 63;
    int wm = wave >> 2, wn = wave & 3;          // 2M x 4N, wave-tile 128x64
    int lrow = lane & 31, lhalf = lane >> 5;

    // R5's proven mapping: b&7 = mtile-low (XCD slot); same-A-panel blocks
    // (4 ntiles x same ksp) share an XCD -> A fetched once (FETCH 65.6MB).
    int b = blockIdx.x;
    int u = b >> 3;
    int col = u & 7;
    int mtile = (u >> 3) * 8 + (b & 7);         // 0..31
    int ntile = col >> 1;                       // 0..3
    int ksp = col & 1;
    int m0 = mtile * 256, n0 = ntile * 256;
    int koff = ksp * (HID1 / 2);

    const unsigned short* Abase = A + (size_t)m0 * K + koff;
    const unsigned short* Bbase = Bt + (size_t)n0 * K + koff;
    unsigned short* Cout = ksp ? Cb : Ca;

    floatx16 acc[4][2] = {};
    const int NT = (HID1 / 2) >> 5;             // 64 tiles of BK=32

    // Prologue: stage tiles 0,1,2; wait tile 0 (8 loads of t1,t2 in flight).
    Q4_STAGE(lds + 0 * 16384, Abase, 0);  Q4_STAGE(lds + 0 * 16384 + 8192, Bbase, 0);
    Q4_STAGE(lds + 1 * 16384, Abase, 32); Q4_STAGE(lds + 1 * 16384 + 8192, Bbase, 32);
    Q4_STAGE(lds + 2 * 16384, Abase, 64); Q4_STAGE(lds + 2 * 16384 + 8192, Bbase, 64);
    asm volatile("s_waitcnt vmcnt(8)" ::: "memory");
    __builtin_amdgcn_s_barrier();

    for (int t = 0; t < NT; t++) {
        const unsigned short* Ak = lds + (size_t)(t & 3) * 16384;
        const unsigned short* Bk = Ak + 8192;
        unsigned short* Lnext = lds + (size_t)((t + 3) & 3) * 16384;
        int k3 = (t + 3) * 32;
#pragma unroll
        for (int kk = 0; kk < 2; kk++) {
            int lc0 = kk * 2 + lhalf;           // 16B chunk 0..3
            bf16x8 af[4], bfr[2];
#pragma unroll
            for (int mt = 0; mt < 4; mt++) {
                int R = wm * 128 + mt * 32 + lrow;
                af[mt] = *(const bf16x8*)&Ak[P8_OFF(R, lc0)];
            }
#pragma unroll
            for (int nt = 0; nt < 2; nt++) {
                int R = wn * 64 + nt * 32 + lrow;
                bfr[nt] = *(const bf16x8*)&Bk[P8_OFF(R, lc0)];
            }
            if (t + 3 < NT) {
                if (kk == 0) Q4_STAGE(Lnext, Abase, k3);
                else         Q4_STAGE(Lnext + 8192, Bbase, k3);
            }
            __builtin_amdgcn_s_setprio(1);
#pragma unroll
            for (int mt = 0; mt < 4; mt++)
#pragma unroll
                for (int nt = 0; nt < 2; nt++)
                    acc[mt][nt] = __builtin_amdgcn_mfma_f32_32x32x16_bf16(
                        af[mt], bfr[nt], acc[mt][nt], 0, 0, 0);
            __builtin_amdgcn_s_setprio(0);
        }
        // Tile boundary: tile t+1's buffer must be fully landed.
        if (t + 3 < NT)
            asm volatile("s_waitcnt vmcnt(8)" ::: "memory");
        else if (t + 2 < NT)
            asm volatile("s_waitcnt vmcnt(4)" ::: "memory");
        else if (t + 1 < NT)
            asm volatile("s_waitcnt vmcnt(0)" ::: "memory");
        __builtin_amdgcn_s_barrier();
    }

#pragma unroll
    for (int mt = 0; mt < 4; mt++) {
#pragma unroll
        for (int nt = 0; nt < 2; nt++) {
            int colc = n0 + wn * 64 + nt * 32 + lrow;
#pragma unroll
            for (int reg = 0; reg < 16; reg++) {
                int row = m0 + wm * 128 + mt * 32 + (reg & 3) + 8 * (reg >> 2) + 4 * lhalf;
                Cout[(size_t)row * N + colc] = f2bf(acc[mt][nt][reg]);
            }
        }
    }
}

// ---------------------------------------------------------------------------
// merge: Cb[i] = bf16(bf2f(Ca[i]) + bf2f(Cb[i]))  (in-place, elementwise)
// ---------------------------------------------------------------------------
__global__ __launch_bounds__(256) void merge_kernel(
        const unsigned short* __restrict__ Ca, unsigned short* __restrict__ Cb) {
    const uint4* a4 = (const uint4*)Ca;
    uint4* b4 = (uint4*)Cb;
    int base = blockIdx.x * 1024 + threadIdx.x;
#pragma unroll
    for (int j = 0; j < 4; j++) {
        int i = base + j * 256;
        float fa[8], fb[8];
        unpack8(a4[i], fa);
        unpack8(b4[i], fb);
#pragma unroll
        for (int k = 0; k < 8; k++) fa[k] += fb[k];
        b4[i] = pack8(fa);
    }
}

// ---------------------------------------------------------------------------
// Final: aggregate h3 (stride 16), add b3, log_softmax per node.
// ---------------------------------------------------------------------------
__global__ void final_kernel(const float* __restrict__ h3, const int* __restrict__ row_ptr,
                             const int* __restrict__ csr_src, const float* __restrict__ csr_w,
                             const int* __restrict__ deg, const float* __restrict__ b3,
                             float* __restrict__ out) {
    int v = blockIdx.x * blockDim.x + threadIdx.x;
    if (v >= N_NODES) return;
    const float4* h4 = (const float4*)h3;
    float sw = 1.0f / (float)(deg[v] + 1);
    float a[12];
    *(float4*)&a[0] = h4[v * 4];
    *(float4*)&a[4] = h4[v * 4 + 1];
    *(float4*)&a[8] = h4[v * 4 + 2];
    float acc[F_OUT];
#pragma unroll
    for (int c = 0; c < F_OUT; c++) acc[c] = b3[c] + sw * a[c];
    int end = row_ptr[v + 1];
    for (int e = row_ptr[v]; e < end; e++) {
        int s = csr_src[e];
        float w = csr_w[e];
        float bsrc[12];
        *(float4*)&bsrc[0] = h4[s * 4];
        *(float4*)&bsrc[4] = h4[s * 4 + 1];
        *(float4*)&bsrc[8] = h4[s * 4 + 2];
#pragma unroll
        for (int c = 0; c < F_OUT; c++) acc[c] += w * bsrc[c];
    }
    float m = acc[0];
#pragma unroll
    for (int c = 1; c < F_OUT; c++) m = fmaxf(m, acc[c]);
    float ssum = 0.0f;
#pragma unroll
    for (int c = 0; c < F_OUT; c++) ssum += expf(acc[c] - m);
    float l = logf(ssum);
#pragma unroll
    for (int c = 0; c < F_OUT; c++) out[v * F_OUT + c] = acc[c] - m - l;
}

// ---------------------------------------------------------------------------
// Launch (9 dispatches + memset)
// ---------------------------------------------------------------------------
extern "C" void kernel_launch(void* const* d_in, const int* in_sizes, int n_in,
                              void* d_out, int out_size, void* d_ws, size_t ws_size,
                              hipStream_t stream) {
    const float* x  = (const float*)d_in[0];
    const float* W1 = (const float*)d_in[1];
    const float* b1 = (const float*)d_in[2];
    const float* W2 = (const float*)d_in[3];
    const float* b2 = (const float*)d_in[4];
    const float* W3 = (const float*)d_in[5];
    const float* b3 = (const float*)d_in[6];
    const int*   ei = (const int*)d_in[7];
    float* out = (float*)d_out;

    char* p = (char*)d_ws;
    int*   deg     = (int*)p;    p += N_NODES * 4;
    int*   cnt     = (int*)p;    p += N_NODES * 4;
    int*   row_ptr = (int*)p;    p += 33024;
    int*   csr_src = (int*)p;    p += N_EDGES * 4;
    float* csr_w   = (float*)p;  p += N_EDGES * 4;
    float* h3      = (float*)p;  p += N_NODES * H3_STRIDE * 4;
    unsigned short* w3b = (unsigned short*)p; p += (F_OUT * W3B_STRIDE * 2 + 255) / 256 * 256;
    unsigned short* xb    = (unsigned short*)p; p += (size_t)N_NODES * F_IN * 2;
    unsigned short* agg_x = (unsigned short*)p; p += (size_t)N_NODES * F_IN * 2;
    unsigned short* W1t   = (unsigned short*)p; p += (size_t)HID1 * F_IN * 2;
    unsigned short* W2t   = (unsigned short*)p; p += (size_t)HID2 * HID1 * 2;
    unsigned short* h1    = (unsigned short*)p; p += (size_t)N_NODES * HID1 * 2;
    unsigned short* h2pre = (unsigned short*)p; p += (size_t)N_NODES * HID2 * 2;
    // k0-partial of gemm2 overlays xb+agg_x (16 MB, dead after gemm1).
    unsigned short* h2a = xb;

    // Graph preprocessing (parallel hist + tiny scan) + conversions
    hipMemsetAsync(deg, 0, N_NODES * sizeof(int), stream);
    hist_kernel<<<N_EDGES / 256, 256, 0, stream>>>(ei, deg);
    scan_kernel<<<1, 1024, 0, stream>>>(deg, row_ptr, cnt);
    megaprep_kernel<<<10497, 256, 0, stream>>>(ei, deg, row_ptr, cnt, csr_src, csr_w,
                                               x, xb, W1, W1t, W2, W2t, W3, w3b);

    // Layer 1: 8-phase pipelined 256^2 GEMM (512 blocks x 512 threads)
    agg1_kernel<<<N_NODES / 4, 256, 0, stream>>>(xb, row_ptr, csr_src, csr_w, deg, agg_x);
    gemm1_pipe8_kernel<<<(N_NODES / 256) * (HID1 / 256), 512, 0, stream>>>(
        agg_x, W1t, b1, h1);

    // Layer 2: split-K=2 quad-buffer GEMM (256 blocks = full chip) + merge
    gemm2_q4_split_kernel<<<256, 512, 0, stream>>>(h1, W2t, h2a, h2pre);
    merge_kernel<<<1024, 256, 0, stream>>>(h2a, h2pre);

    // Layer 2 aggregation + Layer 3 GEMM fused
    agg2_gemm3_kernel<<<N_NODES / 2, 256, 0, stream>>>(h2pre, row_ptr, csr_src, csr_w,
                                                       deg, b2, w3b, h3);

    // Output
    final_kernel<<<N_NODES / 256, 256, 0, stream>>>(h3, row_ptr, csr_src, csr_w, deg, b3, out);
}

// Round 7
// 287.237 us; speedup vs baseline: 1.0090x; 1.0090x over previous
//
#include <hip/hip_runtime.h>
#include <math.h>

#define N_NODES 8192
#define N_EDGES 65536
#define F_IN    512
#define HID1    4096
#define HID2    1024
#define F_OUT   10
#define H3_STRIDE 16
#define W3B_STRIDE 1032   // padded K-stride of bf16 W3^T rows

typedef __bf16 bf16x8 __attribute__((ext_vector_type(8)));
typedef float floatx4 __attribute__((ext_vector_type(4)));
typedef float floatx16 __attribute__((ext_vector_type(16)));

static __device__ __forceinline__ unsigned short f2bf(float f) {
    union { float f; unsigned u; } v; v.f = f;
    unsigned r = v.u + 0x7fffu + ((v.u >> 16) & 1u);   // RNE
    return (unsigned short)(r >> 16);
}
static __device__ __forceinline__ float bf2f(unsigned short u) {
    union { unsigned u; float f; } v; v.u = ((unsigned)u) << 16;
    return v.f;
}
static __device__ __forceinline__ void unpack8(uint4 r, float* f) {
    union { unsigned u; float v; } c;
    c.u = r.x << 16;          f[0] = c.v;
    c.u = r.x & 0xffff0000u;  f[1] = c.v;
    c.u = r.y << 16;          f[2] = c.v;
    c.u = r.y & 0xffff0000u;  f[3] = c.v;
    c.u = r.z << 16;          f[4] = c.v;
    c.u = r.z & 0xffff0000u;  f[5] = c.v;
    c.u = r.w << 16;          f[6] = c.v;
    c.u = r.w & 0xffff0000u;  f[7] = c.v;
}
static __device__ __forceinline__ uint4 pack8(const float* f) {
    uint4 o;
    o.x = (unsigned)f2bf(f[0]) | ((unsigned)f2bf(f[1]) << 16);
    o.y = (unsigned)f2bf(f[2]) | ((unsigned)f2bf(f[3]) << 16);
    o.z = (unsigned)f2bf(f[4]) | ((unsigned)f2bf(f[5]) << 16);
    o.w = (unsigned)f2bf(f[6]) | ((unsigned)f2bf(f[7]) << 16);
    return o;
}

// ---------------------------------------------------------------------------
// hist+scan (one block, R5 version): deg[] via LDS histogram (int4 loads),
// exclusive scan -> row_ptr, cnt[] zeroing. (R6's split version regressed
// -15us: global-atomic hist + memset + extra launches cost more.)
// ---------------------------------------------------------------------------
__global__ __launch_bounds__(1024) void hist_scan_kernel(
        const int* __restrict__ ei, int* __restrict__ deg,
        int* __restrict__ row_ptr, int* __restrict__ cnt) {
    __shared__ int hist[N_NODES];        // 32 KB
    __shared__ int sums[1024];
    int t = threadIdx.x;
#pragma unroll
    for (int i = 0; i < 8; i++) hist[t + i * 1024] = 0;
    __syncthreads();
    const int4* ei4 = (const int4*)(ei + N_EDGES);
#pragma unroll
    for (int i = 0; i < 16; i++) {
        int4 d4 = ei4[i * 1024 + t];
        atomicAdd(&hist[d4.x], 1);
        atomicAdd(&hist[d4.y], 1);
        atomicAdd(&hist[d4.z], 1);
        atomicAdd(&hist[d4.w], 1);
    }
    __syncthreads();
    int base = t * 8;
    int local[8], run = 0;
#pragma unroll
    for (int i = 0; i < 8; i++) {
        int dv = hist[base + i];
        deg[base + i] = dv;
        cnt[base + i] = 0;
        local[i] = run; run += dv;
    }
    sums[t] = run;
    __syncthreads();
    for (int off = 1; off < 1024; off <<= 1) {
        int val = (t >= off) ? sums[t - off] : 0;
        __syncthreads();
        sums[t] += val;
        __syncthreads();
    }
    int offset = (t == 0) ? 0 : sums[t - 1];
#pragma unroll
    for (int i = 0; i < 8; i++) row_ptr[base + i] = offset + local[i];
    if (t == 1023) row_ptr[N_NODES] = sums[1023];
}

// ---------------------------------------------------------------------------
// megaprep: fill CSR (blocks 0..255) + xcvt (256..4351) + W1^T (4352..6399)
// + W2^T (6400..10495) + W3 bf16 cvt (10496). One launch.
// ---------------------------------------------------------------------------
static __device__ __forceinline__ void transpose_body(
        const float* __restrict__ W, unsigned short* __restrict__ Wt,
        int K, int N, int k0, int n0, int tid, float (*t)[33]) {
    int c = tid & 31, r8 = tid >> 5;
#pragma unroll
    for (int i = 0; i < 4; i++) {
        int r = r8 + i * 8;
        t[r][c] = W[(size_t)(k0 + r) * N + n0 + c];
    }
    __syncthreads();
#pragma unroll
    for (int i = 0; i < 4; i++) {
        int r = r8 + i * 8;
        Wt[(size_t)(n0 + r) * K + k0 + c] = f2bf(t[c][r]);
    }
}

__global__ __launch_bounds__(256) void megaprep_kernel(
        const int* __restrict__ ei, const int* __restrict__ deg,
        const int* __restrict__ row_ptr, int* __restrict__ cnt,
        int* __restrict__ csr_src, float* __restrict__ csr_w,
        const float* __restrict__ x, unsigned short* __restrict__ xb,
        const float* __restrict__ W1, unsigned short* __restrict__ W1t,
        const float* __restrict__ W2, unsigned short* __restrict__ W2t,
        const float* __restrict__ W3, unsigned short* __restrict__ w3b) {
    __shared__ float t[32][33];
    int b = blockIdx.x, tid = threadIdx.x;
    if (b < 256) {
        int e = b * 256 + tid;
        int s = ei[e];
        int d = ei[N_EDGES + e];
        int slot = row_ptr[d] + atomicAdd(&cnt[d], 1);
        csr_src[slot] = s;
        csr_w[slot] = rsqrtf((float)((deg[s] + 1) * (deg[d] + 1)));
    } else if (b < 4352) {
        int i = (b - 256) * 256 + tid;
        float4 a = ((const float4*)x)[i];
        ushort4 o;
        o.x = f2bf(a.x); o.y = f2bf(a.y); o.z = f2bf(a.z); o.w = f2bf(a.w);
        ((ushort4*)xb)[i] = o;
    } else if (b < 6400) {
        int bb = b - 4352;                       // W1: K=512, N=4096
        transpose_body(W1, W1t, F_IN, HID1, (bb >> 7) * 32, (bb & 127) * 32, tid, t);
    } else if (b < 10496) {
        int bb = b - 6400;                       // W2: K=4096, N=1024
        transpose_body(W2, W2t, HID1, HID2, (bb >> 5) * 32, (bb & 31) * 32, tid, t);
    } else {
        // W3 [1024,10] f32 -> w3b [10][W3B_STRIDE] bf16 (transposed)
        for (int i = tid; i < HID2 * F_OUT; i += 256) {
            int k = i / F_OUT, c = i % F_OUT;
            w3b[c * W3B_STRIDE + k] = f2bf(W3[i]);
        }
    }
}

// ---------------------------------------------------------------------------
// agg1: agg_x[v,:] = sum_e w_e*xb[src,:] + xb[v,:]/(deg+1) -> bf16
// ---------------------------------------------------------------------------
__global__ __launch_bounds__(256) void agg1_kernel(
        const unsigned short* __restrict__ xb, const int* __restrict__ row_ptr,
        const int* __restrict__ csr_src, const float* __restrict__ csr_w,
        const int* __restrict__ deg, unsigned short* __restrict__ out) {
    int v = blockIdx.x * 4 + (threadIdx.x >> 6);
    int t = threadIdx.x & 63;
    const uint4* xp = (const uint4*)xb;        // row stride 64 uint4
    float sw = 1.0f / (float)(deg[v] + 1);
    float acc[8], tmp[8];
    unpack8(xp[(size_t)v * 64 + t], tmp);
#pragma unroll
    for (int j = 0; j < 8; j++) acc[j] = sw * tmp[j];
    int e = row_ptr[v], end = row_ptr[v + 1];
    for (; e + 4 <= end; e += 4) {
        int s0 = csr_src[e], s1 = csr_src[e + 1];
        int s2 = csr_src[e + 2], s3 = csr_src[e + 3];
        float w0 = csr_w[e], w1 = csr_w[e + 1];
        float w2 = csr_w[e + 2], w3 = csr_w[e + 3];
        float f0[8], f1[8], f2[8], f3[8];
        unpack8(xp[(size_t)s0 * 64 + t], f0);
        unpack8(xp[(size_t)s1 * 64 + t], f1);
        unpack8(xp[(size_t)s2 * 64 + t], f2);
        unpack8(xp[(size_t)s3 * 64 + t], f3);
#pragma unroll
        for (int j = 0; j < 8; j++)
            acc[j] += w0 * f0[j] + w1 * f1[j] + w2 * f2[j] + w3 * f3[j];
    }
    for (; e < end; e++) {
        int s = csr_src[e];
        float w = csr_w[e];
        float f0[8];
        unpack8(xp[(size_t)s * 64 + t], f0);
#pragma unroll
        for (int j = 0; j < 8; j++) acc[j] += w * f0[j];
    }
    ((uint4*)out)[(size_t)v * 64 + t] = pack8(acc);
}

// ---------------------------------------------------------------------------
// agg2 + gemm3 fused.
// ---------------------------------------------------------------------------
__global__ __launch_bounds__(256) void agg2_gemm3_kernel(
        const unsigned short* __restrict__ h, const int* __restrict__ row_ptr,
        const int* __restrict__ csr_src, const float* __restrict__ csr_w,
        const int* __restrict__ deg, const float* __restrict__ b2,
        const unsigned short* __restrict__ w3b, float* __restrict__ H3) {
    __shared__ unsigned short w3s[F_OUT * W3B_STRIDE];   // ~20.2 KB
    __shared__ float red[4][F_OUT];
    int tid = threadIdx.x;
    for (int i = tid; i < F_OUT * W3B_STRIDE; i += 256) w3s[i] = w3b[i];
    __syncthreads();
    int half = tid >> 7;
    int t = tid & 127;
    int v = blockIdx.x * 2 + half;
    const uint4* hp = (const uint4*)h;   // row stride 128 uint4
    float sw = 1.0f / (float)(deg[v] + 1);
    float acc[8], tmp[8];
    unpack8(hp[(size_t)v * 128 + t], tmp);
#pragma unroll
    for (int j = 0; j < 8; j++) acc[j] = sw * tmp[j];
    int e = row_ptr[v], end = row_ptr[v + 1];
    for (; e + 4 <= end; e += 4) {
        int s0 = csr_src[e], s1 = csr_src[e + 1];
        int s2 = csr_src[e + 2], s3 = csr_src[e + 3];
        float w0 = csr_w[e], w1 = csr_w[e + 1];
        float w2 = csr_w[e + 2], w3 = csr_w[e + 3];
        float f0[8], f1[8], f2[8], f3[8];
        unpack8(hp[(size_t)s0 * 128 + t], f0);
        unpack8(hp[(size_t)s1 * 128 + t], f1);
        unpack8(hp[(size_t)s2 * 128 + t], f2);
        unpack8(hp[(size_t)s3 * 128 + t], f3);
#pragma unroll
        for (int j = 0; j < 8; j++)
            acc[j] += w0 * f0[j] + w1 * f1[j] + w2 * f2[j] + w3 * f3[j];
    }
    for (; e < end; e++) {
        int s = csr_src[e];
        float w = csr_w[e];
        float f0[8];
        unpack8(hp[(size_t)s * 128 + t], f0);
#pragma unroll
        for (int j = 0; j < 8; j++) acc[j] += w * f0[j];
    }
    float4 b4a = ((const float4*)b2)[t * 2];
    float4 b4b = ((const float4*)b2)[t * 2 + 1];
    acc[0] = fmaxf(acc[0] + b4a.x, 0.0f); acc[1] = fmaxf(acc[1] + b4a.y, 0.0f);
    acc[2] = fmaxf(acc[2] + b4a.z, 0.0f); acc[3] = fmaxf(acc[3] + b4a.w, 0.0f);
    acc[4] = fmaxf(acc[4] + b4b.x, 0.0f); acc[5] = fmaxf(acc[5] + b4b.y, 0.0f);
    acc[6] = fmaxf(acc[6] + b4b.z, 0.0f); acc[7] = fmaxf(acc[7] + b4b.w, 0.0f);

    float partial[F_OUT];
#pragma unroll
    for (int c = 0; c < F_OUT; c++) {
        float wf[8];
        unpack8(*(const uint4*)&w3s[c * W3B_STRIDE + t * 8], wf);
        partial[c] = acc[0] * wf[0] + acc[1] * wf[1] + acc[2] * wf[2] + acc[3] * wf[3]
                   + acc[4] * wf[4] + acc[5] * wf[5] + acc[6] * wf[6] + acc[7] * wf[7];
    }
#pragma unroll
    for (int c = 0; c < F_OUT; c++) {
#pragma unroll
        for (int off = 32; off > 0; off >>= 1)
            partial[c] += __shfl_xor(partial[c], off, 64);
    }
    int wave = tid >> 6, lane = tid & 63;
    if (lane == 0) {
#pragma unroll
        for (int c = 0; c < F_OUT; c++) red[wave][c] = partial[c];
    }
    __syncthreads();
    if (tid < 2 * F_OUT) {
        int hh = tid / F_OUT, c = tid % F_OUT;
        H3[(size_t)(blockIdx.x * 2 + hh) * H3_STRIDE + c] =
            red[hh * 2][c] + red[hh * 2 + 1][c];
    }
}

// ---------------------------------------------------------------------------
// Shared LDS swizzle pieces (refcheck-verified R4-R6): 256-row x 32-col bf16
// buffer (16 KB), 256B super-rows of 16 chunks, chunk XOR by (row>>2)&3.
// Measured 0 bank conflicts for wave64 b128 reads.
// ---------------------------------------------------------------------------
#define P8_OFF(R_, lc_) ((((R_) >> 2) * 128) + (((((R_) & 3) << 2) | (lc_)) ^ (((R_) >> 2) & 3)) * 8)

#define Q4_STAGE(Lbuf_, base_, k0_) do {                                       \
    unsigned short* L_ = (Lbuf_);                                              \
    _Pragma("unroll")                                                          \
    for (int j = 0; j < 2; j++) {                                              \
        int sl = j * 512 + tid;                                                \
        int s4 = sl >> 4, cs = sl & 15;                                        \
        int csp = cs ^ (s4 & 3);                                               \
        int grow = s4 * 4 + (csp >> 2);                                        \
        int gcol = (csp & 3) * 8;                                              \
        __builtin_amdgcn_global_load_lds(                                      \
            (const __attribute__((address_space(1))) void*)((base_) + (size_t)grow * K + (k0_) + gcol), \
            (__attribute__((address_space(3))) void*)(&L_[sl * 8]), 16, 0, 0); \
    }                                                                          \
} while (0)

// P8 staging (gemm1): buffer index (dbuf,mat,khalf), khalf adds k-offset 32.
#define P8_STAGE(mat_, kh_, dd_, base_, k0_) \
    Q4_STAGE(lds + ((dd_) * 4 + (mat_) * 2 + (kh_)) * 8192, base_, (k0_) + (kh_) * 32)

#define P8_MAIN_LOOP(NT_)                                                      \
    P8_STAGE(0, 0, 0, Abase, 0);                                               \
    P8_STAGE(1, 0, 0, Bbase, 0);                                               \
    P8_STAGE(0, 1, 0, Abase, 0);                                               \
    P8_STAGE(1, 1, 0, Bbase, 0);                                               \
    asm volatile("s_waitcnt vmcnt(4)" ::: "memory");                           \
    __builtin_amdgcn_s_barrier();                                              \
    for (int t = 0; t < (NT_); t++) {                                          \
        int d = t & 1, dn = d ^ 1;                                             \
        int k1 = (t + 1) * 64;                                                 \
        _Pragma("unroll")                                                      \
        for (int kk = 0; kk < 4; kk++) {                                       \
            if (kk == 2) {                                                     \
                if (t + 1 < (NT_))                                             \
                    asm volatile("s_waitcnt vmcnt(4)" ::: "memory");           \
                else                                                           \
                    asm volatile("s_waitcnt vmcnt(0)" ::: "memory");           \
                __builtin_amdgcn_s_barrier();                                  \
            }                                                                  \
            int kh = kk >> 1;                                                  \
            int lc0 = (kk & 1) * 2 + lhalf;                                    \
            const unsigned short* Ak = lds + (d * 4 + kh) * 8192;              \
            const unsigned short* Bk = lds + (d * 4 + 2 + kh) * 8192;          \
            bf16x8 af[4], bfr[2];                                              \
            _Pragma("unroll")                                                  \
            for (int mt = 0; mt < 4; mt++) {                                   \
                int R = wm * 128 + mt * 32 + lrow;                             \
                af[mt] = *(const bf16x8*)&Ak[P8_OFF(R, lc0)];                  \
            }                                                                  \
            _Pragma("unroll")                                                  \
            for (int nt = 0; nt < 2; nt++) {                                   \
                int R = wn * 64 + nt * 32 + lrow;                              \
                bfr[nt] = *(const bf16x8*)&Bk[P8_OFF(R, lc0)];                 \
            }                                                                  \
            if (t + 1 < (NT_)) {                                               \
                if (kk == 0)      P8_STAGE(0, 0, dn, Abase, k1);               \
                else if (kk == 1) P8_STAGE(1, 0, dn, Bbase, k1);               \
                else if (kk == 2) P8_STAGE(0, 1, dn, Abase, k1);               \
                else              P8_STAGE(1, 1, dn, Bbase, k1);               \
            }                                                                  \
            __builtin_amdgcn_s_barrier();                                      \
            __builtin_amdgcn_s_setprio(1);                                     \
            _Pragma("unroll")                                                  \
            for (int mt = 0; mt < 4; mt++)                                     \
                _Pragma("unroll")                                              \
                for (int nt = 0; nt < 2; nt++)                                 \
                    acc[mt][nt] = __builtin_amdgcn_mfma_f32_32x32x16_bf16(     \
                        af[mt], bfr[nt], acc[mt][nt], 0, 0, 0);                \
            __builtin_amdgcn_s_setprio(0);                                     \
            if (kk == 0 || kk == 2) __builtin_amdgcn_s_barrier();              \
        }                                                                      \
        asm volatile("s_waitcnt vmcnt(4)" ::: "memory");                       \
        __builtin_amdgcn_s_barrier();                                          \
    }

// ---------------------------------------------------------------------------
// GEMM1: agg_x[8192,512] @ W1t -> relu(+b1) -> h1 bf16 [8192,4096].
// 512 blocks (16 ntiles x 32 mtiles), 512 threads, 8-phase schedule (R4).
// ---------------------------------------------------------------------------
__global__ __launch_bounds__(512, 2) void gemm1_pipe8_kernel(
        const unsigned short* __restrict__ A,   // [8192,512] bf16
        const unsigned short* __restrict__ Bt,  // [4096,512] bf16
        const float* __restrict__ bias,         // [4096]
        unsigned short* __restrict__ C) {       // [8192,4096] bf16
    __shared__ unsigned short lds[65536];       // 128 KB
    const int K = F_IN, N = HID1;
    int tid = threadIdx.x;
    int wave = tid >> 6, lane = tid & 63;
    int wm = wave >> 2, wn = wave & 3;          // 2M x 4N, wave-tile 128x64
    int lrow = lane & 31, lhalf = lane >> 5;

    int b = blockIdx.x;
    int GN = HID1 >> 8;                         // 16
    int ntile = (b >> 3) % GN;
    int mtile = ((b >> 3) / GN) * 8 + (b & 7);  // 0..31
    int m0 = mtile * 256, n0 = ntile * 256;

    const unsigned short* Abase = A + (size_t)m0 * K;
    const unsigned short* Bbase = Bt + (size_t)n0 * K;

    floatx16 acc[4][2] = {};
    P8_MAIN_LOOP(8)                             // K=512 -> 8 K-tiles

#pragma unroll
    for (int mt = 0; mt < 4; mt++) {
#pragma unroll
        for (int nt = 0; nt < 2; nt++) {
            int col = n0 + wn * 64 + nt * 32 + lrow;
            float bv = bias[col];
#pragma unroll
            for (int reg = 0; reg < 16; reg++) {
                int row = m0 + wm * 128 + mt * 32 + (reg & 3) + 8 * (reg >> 2) + 4 * lhalf;
                float v = fmaxf(acc[mt][nt][reg] + bv, 0.0f);
                C[(size_t)row * N + col] = f2bf(v);
            }
        }
    }
}

// ---------------------------------------------------------------------------
// GEMM2 split-K quad-buffer v2 (R7): same quad-buffer + counted-vmcnt frame
// as R6, but ONE 16-MFMA cluster per tile instead of two 8-MFMA clusters:
// {issue 4 staging gloads for t+3, read all 12 fragments (both k16 steps),
// setprio(1), 16 MFMA, setprio(0), vmcnt+barrier}. Doubles the MFMA cluster
// length the matrix pipe sees per read segment -- isolates cluster-length
// as the variable vs R6 (null barrier test) and R5 (8-phase).
// ---------------------------------------------------------------------------
__global__ __launch_bounds__(512, 2) void gemm2_q4v2_split_kernel(
        const unsigned short* __restrict__ A,   // [8192,4096] bf16 (h1)
        const unsigned short* __restrict__ Bt,  // [1024,4096] bf16 (W2t)
        unsigned short* __restrict__ Ca,        // [8192,1024] bf16 partial k0
        unsigned short* __restrict__ Cb) {      // [8192,1024] bf16 partial k1
    __shared__ unsigned short lds[65536];       // 128 KB = 4 slots x 32 KB
    const int K = HID1;                         // row stride of A and Bt
    const int N = HID2;
    int tid = threadIdx.x;
    int wave = tid >> 6, lane = tid & 63;
    int wm = wave >> 2, wn = wave & 3;          // 2M x 4N, wave-tile 128x64
    int lrow = lane & 31, lhalf = lane >> 5;

    // R5's proven mapping: b&7 = mtile-low (XCD slot shares A panel).
    int b = blockIdx.x;
    int u = b >> 3;
    int col = u & 7;
    int mtile = (u >> 3) * 8 + (b & 7);         // 0..31
    int ntile = col >> 1;                       // 0..3
    int ksp = col & 1;
    int m0 = mtile * 256, n0 = ntile * 256;
    int koff = ksp * (HID1 / 2);

    const unsigned short* Abase = A + (size_t)m0 * K + koff;
    const unsigned short* Bbase = Bt + (size_t)n0 * K + koff;
    unsigned short* Cout = ksp ? Cb : Ca;

    floatx16 acc[4][2] = {};
    const int NT = (HID1 / 2) >> 5;             // 64 tiles of BK=32

    // Prologue: stage tiles 0,1,2; wait tile 0 (8 loads of t1,t2 in flight).
    Q4_STAGE(lds + 0 * 16384, Abase, 0);  Q4_STAGE(lds + 0 * 16384 + 8192, Bbase, 0);
    Q4_STAGE(lds + 1 * 16384, Abase, 32); Q4_STAGE(lds + 1 * 16384 + 8192, Bbase, 32);
    Q4_STAGE(lds + 2 * 16384, Abase, 64); Q4_STAGE(lds + 2 * 16384 + 8192, Bbase, 64);
    asm volatile("s_waitcnt vmcnt(8)" ::: "memory");
    __builtin_amdgcn_s_barrier();

    for (int t = 0; t < NT; t++) {
        const unsigned short* Ak = lds + (size_t)(t & 3) * 16384;
        const unsigned short* Bk = Ak + 8192;
        unsigned short* Lnext = lds + (size_t)((t + 3) & 3) * 16384;
        int k3 = (t + 3) * 32;
        // Issue next-tile staging first: gloads queue under the reads+MFMAs.
        if (t + 3 < NT) {
            Q4_STAGE(Lnext, Abase, k3);
            Q4_STAGE(Lnext + 8192, Bbase, k3);
        }
        // Read ALL fragments for both k16 steps (12 b128).
        bf16x8 af[2][4], bfr[2][2];
#pragma unroll
        for (int kk = 0; kk < 2; kk++) {
            int lc0 = kk * 2 + lhalf;           // 16B chunk 0..3
#pragma unroll
            for (int mt = 0; mt < 4; mt++) {
                int R = wm * 128 + mt * 32 + lrow;
                af[kk][mt] = *(const bf16x8*)&Ak[P8_OFF(R, lc0)];
            }
#pragma unroll
            for (int nt = 0; nt < 2; nt++) {
                int R = wn * 64 + nt * 32 + lrow;
                bfr[kk][nt] = *(const bf16x8*)&Bk[P8_OFF(R, lc0)];
            }
        }
        // One long MFMA cluster: 16 back-to-back.
        __builtin_amdgcn_s_setprio(1);
#pragma unroll
        for (int kk = 0; kk < 2; kk++)
#pragma unroll
            for (int mt = 0; mt < 4; mt++)
#pragma unroll
                for (int nt = 0; nt < 2; nt++)
                    acc[mt][nt] = __builtin_amdgcn_mfma_f32_32x32x16_bf16(
                        af[kk][mt], bfr[kk][nt], acc[mt][nt], 0, 0, 0);
        __builtin_amdgcn_s_setprio(0);
        // Tile boundary: tile t+1's buffer must be fully landed.
        if (t + 3 < NT)
            asm volatile("s_waitcnt vmcnt(8)" ::: "memory");
        else if (t + 2 < NT)
            asm volatile("s_waitcnt vmcnt(4)" ::: "memory");
        else if (t + 1 < NT)
            asm volatile("s_waitcnt vmcnt(0)" ::: "memory");
        __builtin_amdgcn_s_barrier();
    }

#pragma unroll
    for (int mt = 0; mt < 4; mt++) {
#pragma unroll
        for (int nt = 0; nt < 2; nt++) {
            int colc = n0 + wn * 64 + nt * 32 + lrow;
#pragma unroll
            for (int reg = 0; reg < 16; reg++) {
                int row = m0 + wm * 128 + mt * 32 + (reg & 3) + 8 * (reg >> 2) + 4 * lhalf;
                Cout[(size_t)row * N + colc] = f2bf(acc[mt][nt][reg]);
            }
        }
    }
}

// ---------------------------------------------------------------------------
// merge: Cb[i] = bf16(bf2f(Ca[i]) + bf2f(Cb[i]))  (in-place, elementwise)
// ---------------------------------------------------------------------------
__global__ __launch_bounds__(256) void merge_kernel(
        const unsigned short* __restrict__ Ca, unsigned short* __restrict__ Cb) {
    const uint4* a4 = (const uint4*)Ca;
    uint4* b4 = (uint4*)Cb;
    int base = blockIdx.x * 1024 + threadIdx.x;
#pragma unroll
    for (int j = 0; j < 4; j++) {
        int i = base + j * 256;
        float fa[8], fb[8];
        unpack8(a4[i], fa);
        unpack8(b4[i], fb);
#pragma unroll
        for (int k = 0; k < 8; k++) fa[k] += fb[k];
        b4[i] = pack8(fa);
    }
}

// ---------------------------------------------------------------------------
// Final: aggregate h3 (stride 16), add b3, log_softmax per node.
// ---------------------------------------------------------------------------
__global__ void final_kernel(const float* __restrict__ h3, const int* __restrict__ row_ptr,
                             const int* __restrict__ csr_src, const float* __restrict__ csr_w,
                             const int* __restrict__ deg, const float* __restrict__ b3,
                             float* __restrict__ out) {
    int v = blockIdx.x * blockDim.x + threadIdx.x;
    if (v >= N_NODES) return;
    const float4* h4 = (const float4*)h3;
    float sw = 1.0f / (float)(deg[v] + 1);
    float a[12];
    *(float4*)&a[0] = h4[v * 4];
    *(float4*)&a[4] = h4[v * 4 + 1];
    *(float4*)&a[8] = h4[v * 4 + 2];
    float acc[F_OUT];
#pragma unroll
    for (int c = 0; c < F_OUT; c++) acc[c] = b3[c] + sw * a[c];
    int end = row_ptr[v + 1];
    for (int e = row_ptr[v]; e < end; e++) {
        int s = csr_src[e];
        float w = csr_w[e];
        float bsrc[12];
        *(float4*)&bsrc[0] = h4[s * 4];
        *(float4*)&bsrc[4] = h4[s * 4 + 1];
        *(float4*)&bsrc[8] = h4[s * 4 + 2];
#pragma unroll
        for (int c = 0; c < F_OUT; c++) acc[c] += w * bsrc[c];
    }
    float m = acc[0];
#pragma unroll
    for (int c = 1; c < F_OUT; c++) m = fmaxf(m, acc[c]);
    float ssum = 0.0f;
#pragma unroll
    for (int c = 0; c < F_OUT; c++) ssum += expf(acc[c] - m);
    float l = logf(ssum);
#pragma unroll
    for (int c = 0; c < F_OUT; c++) out[v * F_OUT + c] = acc[c] - m - l;
}

// ---------------------------------------------------------------------------
// Launch (8 dispatches)
// ---------------------------------------------------------------------------
extern "C" void kernel_launch(void* const* d_in, const int* in_sizes, int n_in,
                              void* d_out, int out_size, void* d_ws, size_t ws_size,
                              hipStream_t stream) {
    const float* x  = (const float*)d_in[0];
    const float* W1 = (const float*)d_in[1];
    const float* b1 = (const float*)d_in[2];
    const float* W2 = (const float*)d_in[3];
    const float* b2 = (const float*)d_in[4];
    const float* W3 = (const float*)d_in[5];
    const float* b3 = (const float*)d_in[6];
    const int*   ei = (const int*)d_in[7];
    float* out = (float*)d_out;

    char* p = (char*)d_ws;
    int*   deg     = (int*)p;    p += N_NODES * 4;
    int*   cnt     = (int*)p;    p += N_NODES * 4;
    int*   row_ptr = (int*)p;    p += 33024;
    int*   csr_src = (int*)p;    p += N_EDGES * 4;
    float* csr_w   = (float*)p;  p += N_EDGES * 4;
    float* h3      = (float*)p;  p += N_NODES * H3_STRIDE * 4;
    unsigned short* w3b = (unsigned short*)p; p += (F_OUT * W3B_STRIDE * 2 + 255) / 256 * 256;
    unsigned short* xb    = (unsigned short*)p; p += (size_t)N_NODES * F_IN * 2;
    unsigned short* agg_x = (unsigned short*)p; p += (size_t)N_NODES * F_IN * 2;
    unsigned short* W1t   = (unsigned short*)p; p += (size_t)HID1 * F_IN * 2;
    unsigned short* W2t   = (unsigned short*)p; p += (size_t)HID2 * HID1 * 2;
    unsigned short* h1    = (unsigned short*)p; p += (size_t)N_NODES * HID1 * 2;
    unsigned short* h2pre = (unsigned short*)p; p += (size_t)N_NODES * HID2 * 2;
    // k0-partial of gemm2 overlays xb+agg_x (16 MB, dead after gemm1).
    unsigned short* h2a = xb;

    // Graph preprocessing + all conversions (2 launches, R5 structure)
    hist_scan_kernel<<<1, 1024, 0, stream>>>(ei, deg, row_ptr, cnt);
    megaprep_kernel<<<10497, 256, 0, stream>>>(ei, deg, row_ptr, cnt, csr_src, csr_w,
                                               x, xb, W1, W1t, W2, W2t, W3, w3b);

    // Layer 1: 8-phase pipelined 256^2 GEMM (512 blocks x 512 threads)
    agg1_kernel<<<N_NODES / 4, 256, 0, stream>>>(xb, row_ptr, csr_src, csr_w, deg, agg_x);
    gemm1_pipe8_kernel<<<(N_NODES / 256) * (HID1 / 256), 512, 0, stream>>>(
        agg_x, W1t, b1, h1);

    // Layer 2: split-K=2 quad-buffer GEMM v2 (long MFMA cluster) + merge
    gemm2_q4v2_split_kernel<<<256, 512, 0, stream>>>(h1, W2t, h2a, h2pre);
    merge_kernel<<<1024, 256, 0, stream>>>(h2a, h2pre);

    // Layer 2 aggregation + Layer 3 GEMM fused
    agg2_gemm3_kernel<<<N_NODES / 2, 256, 0, stream>>>(h2pre, row_ptr, csr_src, csr_w,
                                                       deg, b2, w3b, h3);

    // Output
    final_kernel<<<N_NODES / 256, 256, 0, stream>>>(h3, row_ptr, csr_src, csr_w, deg, b3, out);
}

// Round 8
// 281.917 us; speedup vs baseline: 1.0281x; 1.0189x over previous
//
#include <hip/hip_runtime.h>
#include <math.h>

#define N_NODES 8192
#define N_EDGES 65536
#define F_IN    512
#define HID1    4096
#define HID2    1024
#define F_OUT   10
#define H3_STRIDE 16

typedef __bf16 bf16x8 __attribute__((ext_vector_type(8)));
typedef float floatx16 __attribute__((ext_vector_type(16)));

static __device__ __forceinline__ unsigned short f2bf(float f) {
    union { float f; unsigned u; } v; v.f = f;
    unsigned r = v.u + 0x7fffu + ((v.u >> 16) & 1u);   // RNE
    return (unsigned short)(r >> 16);
}
static __device__ __forceinline__ void unpack8(uint4 r, float* f) {
    union { unsigned u; float v; } c;
    c.u = r.x << 16;          f[0] = c.v;
    c.u = r.x & 0xffff0000u;  f[1] = c.v;
    c.u = r.y << 16;          f[2] = c.v;
    c.u = r.y & 0xffff0000u;  f[3] = c.v;
    c.u = r.z << 16;          f[4] = c.v;
    c.u = r.z & 0xffff0000u;  f[5] = c.v;
    c.u = r.w << 16;          f[6] = c.v;
    c.u = r.w & 0xffff0000u;  f[7] = c.v;
}
static __device__ __forceinline__ uint4 pack8(const float* f) {
    uint4 o;
    o.x = (unsigned)f2bf(f[0]) | ((unsigned)f2bf(f[1]) << 16);
    o.y = (unsigned)f2bf(f[2]) | ((unsigned)f2bf(f[3]) << 16);
    o.z = (unsigned)f2bf(f[4]) | ((unsigned)f2bf(f[5]) << 16);
    o.w = (unsigned)f2bf(f[6]) | ((unsigned)f2bf(f[7]) << 16);
    return o;
}

// ---------------------------------------------------------------------------
// hist+scan (one block, R5 version — R6's split variant regressed −15us).
// ---------------------------------------------------------------------------
__global__ __launch_bounds__(1024) void hist_scan_kernel(
        const int* __restrict__ ei, int* __restrict__ deg,
        int* __restrict__ row_ptr, int* __restrict__ cnt) {
    __shared__ int hist[N_NODES];        // 32 KB
    __shared__ int sums[1024];
    int t = threadIdx.x;
#pragma unroll
    for (int i = 0; i < 8; i++) hist[t + i * 1024] = 0;
    __syncthreads();
    const int4* ei4 = (const int4*)(ei + N_EDGES);
#pragma unroll
    for (int i = 0; i < 16; i++) {
        int4 d4 = ei4[i * 1024 + t];
        atomicAdd(&hist[d4.x], 1);
        atomicAdd(&hist[d4.y], 1);
        atomicAdd(&hist[d4.z], 1);
        atomicAdd(&hist[d4.w], 1);
    }
    __syncthreads();
    int base = t * 8;
    int local[8], run = 0;
#pragma unroll
    for (int i = 0; i < 8; i++) {
        int dv = hist[base + i];
        deg[base + i] = dv;
        cnt[base + i] = 0;
        local[i] = run; run += dv;
    }
    sums[t] = run;
    __syncthreads();
    for (int off = 1; off < 1024; off <<= 1) {
        int val = (t >= off) ? sums[t - off] : 0;
        __syncthreads();
        sums[t] += val;
        __syncthreads();
    }
    int offset = (t == 0) ? 0 : sums[t - 1];
#pragma unroll
    for (int i = 0; i < 8; i++) row_ptr[base + i] = offset + local[i];
    if (t == 1023) row_ptr[N_NODES] = sums[1023];
}

// ---------------------------------------------------------------------------
// megaprep: fill CSR (blocks 0..255) + xcvt (256..4351) + W1^T (4352..6399)
// + W2^T (6400..10495). One launch. (w3b conversion dropped — agg2_sliced
// reads W3 f32 directly into registers.)
// ---------------------------------------------------------------------------
static __device__ __forceinline__ void transpose_body(
        const float* __restrict__ W, unsigned short* __restrict__ Wt,
        int K, int N, int k0, int n0, int tid, float (*t)[33]) {
    int c = tid & 31, r8 = tid >> 5;
#pragma unroll
    for (int i = 0; i < 4; i++) {
        int r = r8 + i * 8;
        t[r][c] = W[(size_t)(k0 + r) * N + n0 + c];
    }
    __syncthreads();
#pragma unroll
    for (int i = 0; i < 4; i++) {
        int r = r8 + i * 8;
        Wt[(size_t)(n0 + r) * K + k0 + c] = f2bf(t[c][r]);
    }
}

__global__ __launch_bounds__(256) void megaprep_kernel(
        const int* __restrict__ ei, const int* __restrict__ deg,
        const int* __restrict__ row_ptr, int* __restrict__ cnt,
        int* __restrict__ csr_src, float* __restrict__ csr_w,
        const float* __restrict__ x, unsigned short* __restrict__ xb,
        const float* __restrict__ W1, unsigned short* __restrict__ W1t,
        const float* __restrict__ W2, unsigned short* __restrict__ W2t) {
    __shared__ float t[32][33];
    int b = blockIdx.x, tid = threadIdx.x;
    if (b < 256) {
        int e = b * 256 + tid;
        int s = ei[e];
        int d = ei[N_EDGES + e];
        int slot = row_ptr[d] + atomicAdd(&cnt[d], 1);
        csr_src[slot] = s;
        csr_w[slot] = rsqrtf((float)((deg[s] + 1) * (deg[d] + 1)));
    } else if (b < 4352) {
        int i = (b - 256) * 256 + tid;
        float4 a = ((const float4*)x)[i];
        ushort4 o;
        o.x = f2bf(a.x); o.y = f2bf(a.y); o.z = f2bf(a.z); o.w = f2bf(a.w);
        ((ushort4*)xb)[i] = o;
    } else if (b < 6400) {
        int bb = b - 4352;                       // W1: K=512, N=4096
        transpose_body(W1, W1t, F_IN, HID1, (bb >> 7) * 32, (bb & 127) * 32, tid, t);
    } else {
        int bb = b - 6400;                       // W2: K=4096, N=1024
        transpose_body(W2, W2t, HID1, HID2, (bb >> 5) * 32, (bb & 31) * 32, tid, t);
    }
}

// ---------------------------------------------------------------------------
// agg1 sliced (R8): 4 slices x 128 features. Table slice = 8192 x 256B = 2MB,
// L2-resident per XCD pair {s, s+4} (blockIdx&3 = slice, dispatch round-robin).
// 1 node per wave, lane = 2 features (uint). Edge gather hits L2 not L3.
// ---------------------------------------------------------------------------
__global__ __launch_bounds__(256) void agg1_sliced_kernel(
        const unsigned short* __restrict__ xb, const int* __restrict__ row_ptr,
        const int* __restrict__ csr_src, const float* __restrict__ csr_w,
        const int* __restrict__ deg, unsigned short* __restrict__ out) {
    int b = blockIdx.x;
    int slice = b & 3;
    int ng = b >> 2;
    int v = ng * 4 + (threadIdx.x >> 6);
    int lane = threadIdx.x & 63;
    int sbase = slice * 64 + lane;              // uint index in 256-uint row
    const unsigned* xu = (const unsigned*)xb;
    float sw = 1.0f / (float)(deg[v] + 1);
    union { unsigned u; float f; } cv;
    unsigned su = xu[(size_t)v * 256 + sbase];
    float a0, a1;
    cv.u = su << 16;          a0 = sw * cv.f;
    cv.u = su & 0xffff0000u;  a1 = sw * cv.f;
    int e = row_ptr[v], end = row_ptr[v + 1];
    for (; e + 4 <= end; e += 4) {
        int s0 = csr_src[e],     s1 = csr_src[e + 1];
        int s2 = csr_src[e + 2], s3 = csr_src[e + 3];
        float w0 = csr_w[e],     w1 = csr_w[e + 1];
        float w2 = csr_w[e + 2], w3 = csr_w[e + 3];
        unsigned u0 = xu[(size_t)s0 * 256 + sbase];
        unsigned u1 = xu[(size_t)s1 * 256 + sbase];
        unsigned u2 = xu[(size_t)s2 * 256 + sbase];
        unsigned u3 = xu[(size_t)s3 * 256 + sbase];
        cv.u = u0 << 16; a0 += w0 * cv.f;  cv.u = u0 & 0xffff0000u; a1 += w0 * cv.f;
        cv.u = u1 << 16; a0 += w1 * cv.f;  cv.u = u1 & 0xffff0000u; a1 += w1 * cv.f;
        cv.u = u2 << 16; a0 += w2 * cv.f;  cv.u = u2 & 0xffff0000u; a1 += w2 * cv.f;
        cv.u = u3 << 16; a0 += w3 * cv.f;  cv.u = u3 & 0xffff0000u; a1 += w3 * cv.f;
    }
    for (; e < end; e++) {
        int s = csr_src[e]; float w = csr_w[e];
        unsigned u0 = xu[(size_t)s * 256 + sbase];
        cv.u = u0 << 16; a0 += w * cv.f;  cv.u = u0 & 0xffff0000u; a1 += w * cv.f;
    }
    ((unsigned*)out)[(size_t)v * 256 + sbase] =
        (unsigned)f2bf(a0) | ((unsigned)f2bf(a1) << 16);
}

// ---------------------------------------------------------------------------
// agg2+gemm3 sliced (R8): 8 slices x 128 features, blockIdx&7 = slice ->
// table slice 2MB L2-resident per XCD. Per wave: aggregate one node's slice,
// relu(+b2 slice), partial dot with W3 rows (held in registers), 6-level
// shfl reduce, write partial[10] to h3p[slice][v][16].
// ---------------------------------------------------------------------------
__global__ __launch_bounds__(256) void agg2_gemm3_sliced_kernel(
        const unsigned short* __restrict__ h, const int* __restrict__ row_ptr,
        const int* __restrict__ csr_src, const float* __restrict__ csr_w,
        const int* __restrict__ deg, const float* __restrict__ b2,
        const float* __restrict__ W3, float* __restrict__ h3p) {
    int b = blockIdx.x;
    int slice = b & 7;
    int ng = b >> 3;
    int v = ng * 4 + (threadIdx.x >> 6);
    int lane = threadIdx.x & 63;
    int sbase = slice * 64 + lane;              // uint index in 512-uint row
    int f0 = slice * 128 + lane * 2;
    const unsigned* hu = (const unsigned*)h;
    float w3r0[F_OUT], w3r1[F_OUT];
#pragma unroll
    for (int c = 0; c < F_OUT; c++) {
        w3r0[c] = W3[(size_t)f0 * F_OUT + c];
        w3r1[c] = W3[(size_t)(f0 + 1) * F_OUT + c];
    }
    float bv0 = b2[f0], bv1 = b2[f0 + 1];
    float sw = 1.0f / (float)(deg[v] + 1);
    union { unsigned u; float f; } cv;
    unsigned su = hu[(size_t)v * 512 + sbase];
    float a0, a1;
    cv.u = su << 16;          a0 = sw * cv.f;
    cv.u = su & 0xffff0000u;  a1 = sw * cv.f;
    int e = row_ptr[v], end = row_ptr[v + 1];
    for (; e + 4 <= end; e += 4) {
        int s0 = csr_src[e],     s1 = csr_src[e + 1];
        int s2 = csr_src[e + 2], s3 = csr_src[e + 3];
        float w0 = csr_w[e],     w1 = csr_w[e + 1];
        float w2 = csr_w[e + 2], w3 = csr_w[e + 3];
        unsigned u0 = hu[(size_t)s0 * 512 + sbase];
        unsigned u1 = hu[(size_t)s1 * 512 + sbase];
        unsigned u2 = hu[(size_t)s2 * 512 + sbase];
        unsigned u3 = hu[(size_t)s3 * 512 + sbase];
        cv.u = u0 << 16; a0 += w0 * cv.f;  cv.u = u0 & 0xffff0000u; a1 += w0 * cv.f;
        cv.u = u1 << 16; a0 += w1 * cv.f;  cv.u = u1 & 0xffff0000u; a1 += w1 * cv.f;
        cv.u = u2 << 16; a0 += w2 * cv.f;  cv.u = u2 & 0xffff0000u; a1 += w2 * cv.f;
        cv.u = u3 << 16; a0 += w3 * cv.f;  cv.u = u3 & 0xffff0000u; a1 += w3 * cv.f;
    }
    for (; e < end; e++) {
        int s = csr_src[e]; float w = csr_w[e];
        unsigned u0 = hu[(size_t)s * 512 + sbase];
        cv.u = u0 << 16; a0 += w * cv.f;  cv.u = u0 & 0xffff0000u; a1 += w * cv.f;
    }
    a0 = fmaxf(a0 + bv0, 0.0f);
    a1 = fmaxf(a1 + bv1, 0.0f);
    float partial[F_OUT];
#pragma unroll
    for (int c = 0; c < F_OUT; c++) partial[c] = a0 * w3r0[c] + a1 * w3r1[c];
#pragma unroll
    for (int c = 0; c < F_OUT; c++) {
#pragma unroll
        for (int off = 32; off > 0; off >>= 1)
            partial[c] += __shfl_xor(partial[c], off, 64);
    }
    if (lane == 0) {
        float* dst = h3p + ((size_t)slice * N_NODES + v) * H3_STRIDE;
#pragma unroll
        for (int c = 0; c < F_OUT; c++) dst[c] = partial[c];
    }
}

// ---------------------------------------------------------------------------
// reduce_h3: h3[v][0..15] = sum over 8 slices of h3p[s][v][0..15].
// (cols 10..15 are garbage but never consumed by final_kernel.)
// ---------------------------------------------------------------------------
__global__ __launch_bounds__(256) void reduce_h3_kernel(
        const float* __restrict__ h3p, float* __restrict__ h3) {
    int idx = blockIdx.x * 256 + threadIdx.x;   // 32768 = 8192 * 4
    int v = idx >> 2, g = idx & 3;
    const float4* p4 = (const float4*)h3p;
    float4 s = make_float4(0.f, 0.f, 0.f, 0.f);
#pragma unroll
    for (int sl = 0; sl < 8; sl++) {
        float4 a = p4[((size_t)sl * N_NODES + v) * 4 + g];
        s.x += a.x; s.y += a.y; s.z += a.z; s.w += a.w;
    }
    ((float4*)h3)[(size_t)v * 4 + g] = s;
}

// ---------------------------------------------------------------------------
// Shared LDS swizzle pieces (refcheck-verified R4-R7, measured 0 conflicts).
// ---------------------------------------------------------------------------
#define P8_OFF(R_, lc_) ((((R_) >> 2) * 128) + (((((R_) & 3) << 2) | (lc_)) ^ (((R_) >> 2) & 3)) * 8)

#define Q4_STAGE(Lbuf_, base_, k0_) do {                                       \
    unsigned short* L_ = (Lbuf_);                                              \
    _Pragma("unroll")                                                          \
    for (int j = 0; j < 2; j++) {                                              \
        int sl = j * 512 + tid;                                                \
        int s4 = sl >> 4, cs = sl & 15;                                        \
        int csp = cs ^ (s4 & 3);                                               \
        int grow = s4 * 4 + (csp >> 2);                                        \
        int gcol = (csp & 3) * 8;                                              \
        __builtin_amdgcn_global_load_lds(                                      \
            (const __attribute__((address_space(1))) void*)((base_) + (size_t)grow * K + (k0_) + gcol), \
            (__attribute__((address_space(3))) void*)(&L_[sl * 8]), 16, 0, 0); \
    }                                                                          \
} while (0)

#define P8_STAGE(mat_, kh_, dd_, base_, k0_) \
    Q4_STAGE(lds + ((dd_) * 4 + (mat_) * 2 + (kh_)) * 8192, base_, (k0_) + (kh_) * 32)

#define P8_MAIN_LOOP(NT_)                                                      \
    P8_STAGE(0, 0, 0, Abase, 0);                                               \
    P8_STAGE(1, 0, 0, Bbase, 0);                                               \
    P8_STAGE(0, 1, 0, Abase, 0);                                               \
    P8_STAGE(1, 1, 0, Bbase, 0);                                               \
    asm volatile("s_waitcnt vmcnt(4)" ::: "memory");                           \
    __builtin_amdgcn_s_barrier();                                              \
    for (int t = 0; t < (NT_); t++) {                                          \
        int d = t & 1, dn = d ^ 1;                                             \
        int k1 = (t + 1) * 64;                                                 \
        _Pragma("unroll")                                                      \
        for (int kk = 0; kk < 4; kk++) {                                       \
            if (kk == 2) {                                                     \
                if (t + 1 < (NT_))                                             \
                    asm volatile("s_waitcnt vmcnt(4)" ::: "memory");           \
                else                                                           \
                    asm volatile("s_waitcnt vmcnt(0)" ::: "memory");           \
                __builtin_amdgcn_s_barrier();                                  \
            }                                                                  \
            int kh = kk >> 1;                                                  \
            int lc0 = (kk & 1) * 2 + lhalf;                                    \
            const unsigned short* Ak = lds + (d * 4 + kh) * 8192;              \
            const unsigned short* Bk = lds + (d * 4 + 2 + kh) * 8192;          \
            bf16x8 af[4], bfr[2];                                              \
            _Pragma("unroll")                                                  \
            for (int mt = 0; mt < 4; mt++) {                                   \
                int R = wm * 128 + mt * 32 + lrow;                             \
                af[mt] = *(const bf16x8*)&Ak[P8_OFF(R, lc0)];                  \
            }                                                                  \
            _Pragma("unroll")                                                  \
            for (int nt = 0; nt < 2; nt++) {                                   \
                int R = wn * 64 + nt * 32 + lrow;                              \
                bfr[nt] = *(const bf16x8*)&Bk[P8_OFF(R, lc0)];                 \
            }                                                                  \
            if (t + 1 < (NT_)) {                                               \
                if (kk == 0)      P8_STAGE(0, 0, dn, Abase, k1);               \
                else if (kk == 1) P8_STAGE(1, 0, dn, Bbase, k1);               \
                else if (kk == 2) P8_STAGE(0, 1, dn, Abase, k1);               \
                else              P8_STAGE(1, 1, dn, Bbase, k1);               \
            }                                                                  \
            __builtin_amdgcn_s_barrier();                                      \
            __builtin_amdgcn_s_setprio(1);                                     \
            _Pragma("unroll")                                                  \
            for (int mt = 0; mt < 4; mt++)                                     \
                _Pragma("unroll")                                              \
                for (int nt = 0; nt < 2; nt++)                                 \
                    acc[mt][nt] = __builtin_amdgcn_mfma_f32_32x32x16_bf16(     \
                        af[mt], bfr[nt], acc[mt][nt], 0, 0, 0);                \
            __builtin_amdgcn_s_setprio(0);                                     \
            if (kk == 0 || kk == 2) __builtin_amdgcn_s_barrier();              \
        }                                                                      \
        asm volatile("s_waitcnt vmcnt(4)" ::: "memory");                       \
        __builtin_amdgcn_s_barrier();                                          \
    }

// ---------------------------------------------------------------------------
// GEMM1: agg_x[8192,512] @ W1t -> relu(+b1) -> h1 bf16 [8192,4096].
// 512 blocks, 512 threads, 8-phase schedule (R4, refcheck-verified).
// ---------------------------------------------------------------------------
__global__ __launch_bounds__(512, 2) void gemm1_pipe8_kernel(
        const unsigned short* __restrict__ A,   // [8192,512] bf16
        const unsigned short* __restrict__ Bt,  // [4096,512] bf16
        const float* __restrict__ bias,         // [4096]
        unsigned short* __restrict__ C) {       // [8192,4096] bf16
    __shared__ unsigned short lds[65536];       // 128 KB
    const int K = F_IN, N = HID1;
    int tid = threadIdx.x;
    int wave = tid >> 6, lane = tid & 63;
    int wm = wave >> 2, wn = wave & 3;          // 2M x 4N, wave-tile 128x64
    int lrow = lane & 31, lhalf = lane >> 5;

    int b = blockIdx.x;
    int GN = HID1 >> 8;                         // 16
    int ntile = (b >> 3) % GN;
    int mtile = ((b >> 3) / GN) * 8 + (b & 7);  // 0..31
    int m0 = mtile * 256, n0 = ntile * 256;

    const unsigned short* Abase = A + (size_t)m0 * K;
    const unsigned short* Bbase = Bt + (size_t)n0 * K;

    floatx16 acc[4][2] = {};
    P8_MAIN_LOOP(8)                             // K=512 -> 8 K-tiles

#pragma unroll
    for (int mt = 0; mt < 4; mt++) {
#pragma unroll
        for (int nt = 0; nt < 2; nt++) {
            int col = n0 + wn * 64 + nt * 32 + lrow;
            float bv = bias[col];
#pragma unroll
            for (int reg = 0; reg < 16; reg++) {
                int row = m0 + wm * 128 + mt * 32 + (reg & 3) + 8 * (reg >> 2) + 4 * lhalf;
                float v = fmaxf(acc[mt][nt][reg] + bv, 0.0f);
                C[(size_t)row * N + col] = f2bf(v);
            }
        }
    }
}

// ---------------------------------------------------------------------------
// GEMM2 split-K quad-buffer (R6 verbatim — best measured: 70.0us, 42% Mfma,
// 0 conflicts). BK=32, 4 slots, prefetch 3 ahead, one barrier/tile,
// counted vmcnt(8)/4/0 tail.
// ---------------------------------------------------------------------------
__global__ __launch_bounds__(512, 2) void gemm2_q4_split_kernel(
        const unsigned short* __restrict__ A,   // [8192,4096] bf16 (h1)
        const unsigned short* __restrict__ Bt,  // [1024,4096] bf16 (W2t)
        unsigned short* __restrict__ Ca,        // [8192,1024] bf16 partial k0
        unsigned short* __restrict__ Cb) {      // [8192,1024] bf16 partial k1
    __shared__ unsigned short lds[65536];       // 128 KB = 4 slots x 32 KB
    const int K = HID1;
    const int N = HID2;
    int tid = threadIdx.x;
    int wave = tid >> 6, lane = tid & 63;
    int wm = wave >> 2, wn = wave & 3;          // 2M x 4N, wave-tile 128x64
    int lrow = lane & 31, lhalf = lane >> 5;

    int b = blockIdx.x;
    int u = b >> 3;
    int col = u & 7;
    int mtile = (u >> 3) * 8 + (b & 7);         // 0..31
    int ntile = col >> 1;                       // 0..3
    int ksp = col & 1;
    int m0 = mtile * 256, n0 = ntile * 256;
    int koff = ksp * (HID1 / 2);

    const unsigned short* Abase = A + (size_t)m0 * K + koff;
    const unsigned short* Bbase = Bt + (size_t)n0 * K + koff;
    unsigned short* Cout = ksp ? Cb : Ca;

    floatx16 acc[4][2] = {};
    const int NT = (HID1 / 2) >> 5;             // 64 tiles of BK=32

    Q4_STAGE(lds + 0 * 16384, Abase, 0);  Q4_STAGE(lds + 0 * 16384 + 8192, Bbase, 0);
    Q4_STAGE(lds + 1 * 16384, Abase, 32); Q4_STAGE(lds + 1 * 16384 + 8192, Bbase, 32);
    Q4_STAGE(lds + 2 * 16384, Abase, 64); Q4_STAGE(lds + 2 * 16384 + 8192, Bbase, 64);
    asm volatile("s_waitcnt vmcnt(8)" ::: "memory");
    __builtin_amdgcn_s_barrier();

    for (int t = 0; t < NT; t++) {
        const unsigned short* Ak = lds + (size_t)(t & 3) * 16384;
        const unsigned short* Bk = Ak + 8192;
        unsigned short* Lnext = lds + (size_t)((t + 3) & 3) * 16384;
        int k3 = (t + 3) * 32;
#pragma unroll
        for (int kk = 0; kk < 2; kk++) {
            int lc0 = kk * 2 + lhalf;
            bf16x8 af[4], bfr[2];
#pragma unroll
            for (int mt = 0; mt < 4; mt++) {
                int R = wm * 128 + mt * 32 + lrow;
                af[mt] = *(const bf16x8*)&Ak[P8_OFF(R, lc0)];
            }
#pragma unroll
            for (int nt = 0; nt < 2; nt++) {
                int R = wn * 64 + nt * 32 + lrow;
                bfr[nt] = *(const bf16x8*)&Bk[P8_OFF(R, lc0)];
            }
            if (t + 3 < NT) {
                if (kk == 0) Q4_STAGE(Lnext, Abase, k3);
                else         Q4_STAGE(Lnext + 8192, Bbase, k3);
            }
            __builtin_amdgcn_s_setprio(1);
#pragma unroll
            for (int mt = 0; mt < 4; mt++)
#pragma unroll
                for (int nt = 0; nt < 2; nt++)
                    acc[mt][nt] = __builtin_amdgcn_mfma_f32_32x32x16_bf16(
                        af[mt], bfr[nt], acc[mt][nt], 0, 0, 0);
            __builtin_amdgcn_s_setprio(0);
        }
        if (t + 3 < NT)
            asm volatile("s_waitcnt vmcnt(8)" ::: "memory");
        else if (t + 2 < NT)
            asm volatile("s_waitcnt vmcnt(4)" ::: "memory");
        else if (t + 1 < NT)
            asm volatile("s_waitcnt vmcnt(0)" ::: "memory");
        __builtin_amdgcn_s_barrier();
    }

#pragma unroll
    for (int mt = 0; mt < 4; mt++) {
#pragma unroll
        for (int nt = 0; nt < 2; nt++) {
            int colc = n0 + wn * 64 + nt * 32 + lrow;
#pragma unroll
            for (int reg = 0; reg < 16; reg++) {
                int row = m0 + wm * 128 + mt * 32 + (reg & 3) + 8 * (reg >> 2) + 4 * lhalf;
                Cout[(size_t)row * N + colc] = f2bf(acc[mt][nt][reg]);
            }
        }
    }
}

// ---------------------------------------------------------------------------
// merge: Cb[i] = bf16(bf2f(Ca[i]) + bf2f(Cb[i]))  (in-place, elementwise)
// ---------------------------------------------------------------------------
__global__ __launch_bounds__(256) void merge_kernel(
        const unsigned short* __restrict__ Ca, unsigned short* __restrict__ Cb) {
    const uint4* a4 = (const uint4*)Ca;
    uint4* b4 = (uint4*)Cb;
    int base = blockIdx.x * 1024 + threadIdx.x;
#pragma unroll
    for (int j = 0; j < 4; j++) {
        int i = base + j * 256;
        float fa[8], fb[8];
        unpack8(a4[i], fa);
        unpack8(b4[i], fb);
#pragma unroll
        for (int k = 0; k < 8; k++) fa[k] += fb[k];
        b4[i] = pack8(fa);
    }
}

// ---------------------------------------------------------------------------
// Final: aggregate h3 (stride 16), add b3, log_softmax per node.
// ---------------------------------------------------------------------------
__global__ void final_kernel(const float* __restrict__ h3, const int* __restrict__ row_ptr,
                             const int* __restrict__ csr_src, const float* __restrict__ csr_w,
                             const int* __restrict__ deg, const float* __restrict__ b3,
                             float* __restrict__ out) {
    int v = blockIdx.x * blockDim.x + threadIdx.x;
    if (v >= N_NODES) return;
    const float4* h4 = (const float4*)h3;
    float sw = 1.0f / (float)(deg[v] + 1);
    float a[12];
    *(float4*)&a[0] = h4[v * 4];
    *(float4*)&a[4] = h4[v * 4 + 1];
    *(float4*)&a[8] = h4[v * 4 + 2];
    float acc[F_OUT];
#pragma unroll
    for (int c = 0; c < F_OUT; c++) acc[c] = b3[c] + sw * a[c];
    int end = row_ptr[v + 1];
    for (int e = row_ptr[v]; e < end; e++) {
        int s = csr_src[e];
        float w = csr_w[e];
        float bsrc[12];
        *(float4*)&bsrc[0] = h4[s * 4];
        *(float4*)&bsrc[4] = h4[s * 4 + 1];
        *(float4*)&bsrc[8] = h4[s * 4 + 2];
#pragma unroll
        for (int c = 0; c < F_OUT; c++) acc[c] += w * bsrc[c];
    }
    float m = acc[0];
#pragma unroll
    for (int c = 1; c < F_OUT; c++) m = fmaxf(m, acc[c]);
    float ssum = 0.0f;
#pragma unroll
    for (int c = 0; c < F_OUT; c++) ssum += expf(acc[c] - m);
    float l = logf(ssum);
#pragma unroll
    for (int c = 0; c < F_OUT; c++) out[v * F_OUT + c] = acc[c] - m - l;
}

// ---------------------------------------------------------------------------
// Launch (9 dispatches)
// ---------------------------------------------------------------------------
extern "C" void kernel_launch(void* const* d_in, const int* in_sizes, int n_in,
                              void* d_out, int out_size, void* d_ws, size_t ws_size,
                              hipStream_t stream) {
    const float* x  = (const float*)d_in[0];
    const float* W1 = (const float*)d_in[1];
    const float* b1 = (const float*)d_in[2];
    const float* W2 = (const float*)d_in[3];
    const float* b2 = (const float*)d_in[4];
    const float* W3 = (const float*)d_in[5];
    const float* b3 = (const float*)d_in[6];
    const int*   ei = (const int*)d_in[7];
    float* out = (float*)d_out;

    char* p = (char*)d_ws;
    int*   deg     = (int*)p;    p += N_NODES * 4;
    int*   cnt     = (int*)p;    p += N_NODES * 4;
    int*   row_ptr = (int*)p;    p += 33024;
    int*   csr_src = (int*)p;    p += N_EDGES * 4;
    float* csr_w   = (float*)p;  p += N_EDGES * 4;
    float* h3      = (float*)p;  p += N_NODES * H3_STRIDE * 4;
    unsigned short* xb    = (unsigned short*)p; p += (size_t)N_NODES * F_IN * 2;
    unsigned short* agg_x = (unsigned short*)p; p += (size_t)N_NODES * F_IN * 2;
    unsigned short* W1t   = (unsigned short*)p; p += (size_t)HID1 * F_IN * 2;
    unsigned short* W2t   = (unsigned short*)p; p += (size_t)HID2 * HID1 * 2;
    unsigned short* h1    = (unsigned short*)p; p += (size_t)N_NODES * HID1 * 2;
    unsigned short* h2pre = (unsigned short*)p; p += (size_t)N_NODES * HID2 * 2;
    // Overlays on xb+agg_x (16 MB, dead after gemm1 consumes agg_x):
    unsigned short* h2a = xb;            // gemm2 k0-partial (16 MB)
    float* h3p = (float*)xb;             // agg2 partials (4 MB, after merge)

    // Graph preprocessing + all conversions (2 launches)
    hist_scan_kernel<<<1, 1024, 0, stream>>>(ei, deg, row_ptr, cnt);
    megaprep_kernel<<<10496, 256, 0, stream>>>(ei, deg, row_ptr, cnt, csr_src, csr_w,
                                               x, xb, W1, W1t, W2, W2t);

    // Layer 1: sliced aggregation (L2-resident gather) + 8-phase GEMM
    agg1_sliced_kernel<<<N_NODES / 4 * 4, 256, 0, stream>>>(
        xb, row_ptr, csr_src, csr_w, deg, agg_x);
    gemm1_pipe8_kernel<<<(N_NODES / 256) * (HID1 / 256), 512, 0, stream>>>(
        agg_x, W1t, b1, h1);

    // Layer 2: split-K=2 quad-buffer GEMM (R6 best) + merge
    gemm2_q4_split_kernel<<<256, 512, 0, stream>>>(h1, W2t, h2a, h2pre);
    merge_kernel<<<1024, 256, 0, stream>>>(h2a, h2pre);

    // Layer 2 aggregation + Layer 3 partial GEMM (sliced, L2-resident) + reduce
    agg2_gemm3_sliced_kernel<<<N_NODES / 4 * 8, 256, 0, stream>>>(
        h2pre, row_ptr, csr_src, csr_w, deg, b2, W3, h3p);
    reduce_h3_kernel<<<N_NODES * 4 / 256, 256, 0, stream>>>(h3p, h3);

    // Output
    final_kernel<<<N_NODES / 256, 256, 0, stream>>>(h3, row_ptr, csr_src, csr_w, deg, b3, out);
}